// Round 13
// baseline (329.195 us; speedup 1.0000x reference)
//
#include <hip/hip_runtime.h>

#define BATCH 8192
#define DIM 128
#define NREL 1000
#define MARGIN 1.0f
#define GRID 1400        // 175 * 8, bijective XCD swizzle
#define ORDER_CAP 11264  // >= max padded total (8192 + 3*1000 = 11192)
#define REPEAT 6         // diagnostic: lifts each score dispatch above the
                         // ~40us harness fillBuffer rows in rocprof top-5

// ws layout (4 B units): pA | pB | scratchA | scratchB | order
#define WS_PA 0
#define WS_PB 8192
#define WS_SA 16384
#define WS_SB 24576
#define WS_ORDER 32768

// Fused single-block counting sort (R7-proven): zero+count+pad4-scan+scatter.
__global__ __launch_bounds__(1024) void sort_kernel(const int* __restrict__ r_idx,
                                                    int* __restrict__ order) {
  __shared__ int s_cnt[1024];
  __shared__ int s_cur[1024];
  __shared__ int s_wsum[16];
  const int tid = threadIdx.x, lane = tid & 63, wave = tid >> 6;
  s_cnt[tid] = 0;
  __syncthreads();
  int my[8];
#pragma unroll
  for (int k = 0; k < 8; ++k) {
    my[k] = r_idx[tid + k * 1024];
    atomicAdd(&s_cnt[my[k]], 1);
  }
  __syncthreads();
  const int c = (s_cnt[tid] + 3) & ~3;
  int v = c;
#pragma unroll
  for (int o = 1; o < 64; o <<= 1) {
    int u = __shfl_up(v, o, 64);
    if (lane >= o) v += u;
  }
  if (lane == 63) s_wsum[wave] = v;
  __syncthreads();
  int woff = 0;
  for (int w = 0; w < wave; ++w) woff += s_wsum[w];
  s_cur[tid] = woff + v - c;
  for (int i = tid; i < ORDER_CAP; i += 1024) order[i] = -1;
  __syncthreads();
#pragma unroll
  for (int k = 0; k < 8; ++k) {
    int p = atomicAdd(&s_cur[my[k]], 1);
    order[p] = tid + k * 1024;
  }
}

__device__ inline float2 dvec(const float* __restrict__ b, int c0) {
  float2 h = *(const float2*)(b + c0);
  float2 r = *(const float2*)(b + DIM + c0);
  float2 t = *(const float2*)(b + 2 * DIM + c0);
  return make_float2(fabsf(h.x + r.x - t.x), fabsf(h.y + r.y - t.y));
}

// R7 structure, template<V> ablation:
//  V0 = full | V1 = no LDS stage/reads (register dummy d) |
//  V2 = no W loads (constant wv) | V3 = loads kept, FMA body stripped.
template <int V>
__global__ __launch_bounds__(256) void score_kernel(
    const float* __restrict__ pos_b, const float* __restrict__ neg_b,
    const int* __restrict__ r_idx, const float* __restrict__ rel_emb,
    const int* __restrict__ order, float* __restrict__ pA,
    float* __restrict__ pB) {
  __shared__ float s_d[4][64 * 20];  // kept in ALL variants (same occupancy)
  const int tid = threadIdx.x, lane = tid & 63, wave = tid >> 6;
  const int phys = blockIdx.x;
  const int lb = (phys & 7) * (GRID / 8) + (phys >> 3);
  const int pair = wave >> 1, half = wave & 1;
  const int g = lb * 2 + pair;
  int4 es = *(const int4*)(order + g * 4);
  if (es.x < 0) return;

  const int c0 = lane * 2;
  const int r = r_idx[es.x];
  const bool v1 = es.y >= 0, v2 = es.z >= 0, v3 = es.w >= 0;
  const int e1 = v1 ? es.y : es.x, e2 = v2 ? es.z : es.x, e3 = v3 ? es.w : es.x;

  const float2 z = make_float2(0.f, 0.f);
  float2 dp0 = dvec(pos_b + (size_t)es.x * 3 * DIM, c0);
  float2 dn0 = dvec(neg_b + (size_t)es.x * 3 * DIM, c0);
  float2 dp1 = v1 ? dvec(pos_b + (size_t)e1 * 3 * DIM, c0) : z;
  float2 dn1 = v1 ? dvec(neg_b + (size_t)e1 * 3 * DIM, c0) : z;
  float2 dp2 = v2 ? dvec(pos_b + (size_t)e2 * 3 * DIM, c0) : z;
  float2 dn2 = v2 ? dvec(neg_b + (size_t)e2 * 3 * DIM, c0) : z;
  float2 dp3 = v3 ? dvec(pos_b + (size_t)e3 * 3 * DIM, c0) : z;
  float2 dn3 = v3 ? dvec(neg_b + (size_t)e3 * 3 * DIM, c0) : z;

  const int colb = (lane & 31) * 4;
  const int rsel = lane >> 5;
  const float* W = rel_emb + (size_t)r * (DIM * DIM) +
                   (size_t)(half * 64 + rsel) * DIM + colb;
  const float* dptr = &s_d[wave][(half * 32) * 20 + rsel * 8];

  float s0, s1, s2, s3;

  for (int rep = 0; rep < REPEAT; ++rep) {
    if (V != 1) {
      float* myd = &s_d[wave][lane * 20];
      *(float4*)(myd + 0)  = make_float4(dp0.x, dp1.x, dp2.x, dp3.x);
      *(float4*)(myd + 4)  = make_float4(dn0.x, dn1.x, dn2.x, dn3.x);
      *(float4*)(myd + 8)  = make_float4(dp0.y, dp1.y, dp2.y, dp3.y);
      *(float4*)(myd + 12) = make_float4(dn0.y, dn1.y, dn2.y, dn3.y);
    }

    const float4 fz = make_float4(0.f, 0.f, 0.f, 0.f);
    float4 ap0 = fz, ap1 = fz, ap2 = fz, ap3 = fz;
    float4 an0 = fz, an1 = fz, an2 = fz, an3 = fz;

#define FMA4(ACC, D, WV)          \
  ACC.x = fmaf(D, WV.x, ACC.x);   \
  ACC.y = fmaf(D, WV.y, ACC.y);   \
  ACC.z = fmaf(D, WV.z, ACC.z);   \
  ACC.w = fmaf(D, WV.w, ACC.w);

#pragma unroll 8
    for (int it = 0; it < 32; ++it) {
      float4 wv;
      if (V != 2) wv = *(const float4*)(W + (size_t)(it * 2) * DIM);
      else        wv = make_float4(1.f, 2.f, 3.f, 4.f);
      float4 ddp, ddn;
      if (V != 1) {
        ddp = *(const float4*)(dptr + it * 20);
        ddn = *(const float4*)(dptr + it * 20 + 4);
      } else {
        ddp = make_float4(dp0.x, dp1.x, dp2.x, dp3.x);
        ddn = make_float4(dn0.x, dn1.x, dn2.x, dn3.x);
      }
      if (V == 3) {
        // memory skeleton: consume both load streams, minimal VALU
        ap0.x += wv.x + ddp.x + ddn.x;
      } else {
        FMA4(ap0, ddp.x, wv) FMA4(ap1, ddp.y, wv)
        FMA4(ap2, ddp.z, wv) FMA4(ap3, ddp.w, wv)
        FMA4(an0, ddn.x, wv) FMA4(an1, ddn.y, wv)
        FMA4(an2, ddn.z, wv) FMA4(an3, ddn.w, wv)
      }
    }
#undef FMA4

    const int sl0 = (lane & 31) * 2, sl1 = sl0 + 1;
#define GET4(OUT0, OUT1, OUT2, OUT3, VV)  \
    OUT0 = __shfl(VV.x, sl0, 64);         \
    OUT1 = __shfl(VV.y, sl0, 64);         \
    OUT2 = __shfl(VV.x, sl1, 64);         \
    OUT3 = __shfl(VV.y, sl1, 64);
    float a, b, c, d, e, f, gg, h;
    GET4(a, b, c, d, dp0) GET4(e, f, gg, h, dn0)
    s0 = ap0.x * a + ap0.y * b + ap0.z * c + ap0.w * d -
         (an0.x * e + an0.y * f + an0.z * gg + an0.w * h);
    GET4(a, b, c, d, dp1) GET4(e, f, gg, h, dn1)
    s1 = ap1.x * a + ap1.y * b + ap1.z * c + ap1.w * d -
         (an1.x * e + an1.y * f + an1.z * gg + an1.w * h);
    GET4(a, b, c, d, dp2) GET4(e, f, gg, h, dn2)
    s2 = ap2.x * a + ap2.y * b + ap2.z * c + ap2.w * d -
         (an2.x * e + an2.y * f + an2.z * gg + an2.w * h);
    GET4(a, b, c, d, dp3) GET4(e, f, gg, h, dn3)
    s3 = ap3.x * a + ap3.y * b + ap3.z * c + ap3.w * d -
         (an3.x * e + an3.y * f + an3.z * gg + an3.w * h);
#undef GET4

#pragma unroll
    for (int o = 32; o > 0; o >>= 1) {
      s0 += __shfl_xor(s0, o, 64);
      s1 += __shfl_xor(s1, o, 64);
      s2 += __shfl_xor(s2, o, 64);
      s3 += __shfl_xor(s3, o, 64);
    }
  }  // REPEAT

  float* P = half ? pB : pA;
  if (lane == 0) {
    P[es.x] = s0;
    if (v1) P[es.y] = s1;
    if (v2) P[es.z] = s2;
    if (v3) P[es.w] = s3;
  }
}

__global__ __launch_bounds__(256) void reduce_kernel(const float* __restrict__ pA,
                                                     const float* __restrict__ pB,
                                                     float* __restrict__ out) {
  float acc = 0.f;
  for (int i = threadIdx.x; i < BATCH; i += 256) {
    float v = MARGIN + pA[i] + pB[i];
    acc += (v > 0.f) ? v : 0.f;
  }
#pragma unroll
  for (int o = 32; o > 0; o >>= 1) acc += __shfl_xor(acc, o, 64);
  __shared__ float s[4];
  const int lane = threadIdx.x & 63, wave = threadIdx.x >> 6;
  if (lane == 0) s[wave] = acc;
  __syncthreads();
  if (threadIdx.x == 0) out[0] = (s[0] + s[1] + s[2] + s[3]) * (1.0f / BATCH);
}

extern "C" void kernel_launch(void* const* d_in, const int* in_sizes, int n_in,
                              void* d_out, int out_size, void* d_ws, size_t ws_size,
                              hipStream_t stream) {
  const float* pos_b = (const float*)d_in[0];
  const float* neg_b = (const float*)d_in[1];
  const int* r_idx = (const int*)d_in[2];
  const float* rel_emb = (const float*)d_in[3];
  float* out = (float*)d_out;

  float* pA = (float*)d_ws + WS_PA;
  float* pB = (float*)d_ws + WS_PB;
  float* sA = (float*)d_ws + WS_SA;
  float* sB = (float*)d_ws + WS_SB;
  int* order = (int*)d_ws + WS_ORDER;

  sort_kernel<<<1, 1024, 0, stream>>>(r_idx, order);
  // Ablation dispatches (write scratch), then the real V0 (writes pA/pB).
  score_kernel<3><<<GRID, 256, 0, stream>>>(pos_b, neg_b, r_idx, rel_emb,
                                            order, sA, sB);
  score_kernel<2><<<GRID, 256, 0, stream>>>(pos_b, neg_b, r_idx, rel_emb,
                                            order, sA, sB);
  score_kernel<1><<<GRID, 256, 0, stream>>>(pos_b, neg_b, r_idx, rel_emb,
                                            order, sA, sB);
  score_kernel<0><<<GRID, 256, 0, stream>>>(pos_b, neg_b, r_idx, rel_emb,
                                            order, pA, pB);
  reduce_kernel<<<1, 256, 0, stream>>>(pA, pB, out);
}

// Round 14
// 48.529 us; speedup vs baseline: 6.7835x; 6.7835x over previous
//
#include <hip/hip_runtime.h>

#define BATCH 8192
#define DIM 128
#define NREL 1000
#define MARGIN 1.0f
#define GRID 952         // 8*119 blocks; 952*2 = 1904 >= 1899 max padded groups
#define ORDER_CAP 15232  // GRID*2*8 slots >= 1899*8 = 15192

// ws layout (4 B units): pA[8192] | pB[8192] | order[15232]
#define WS_PA 0
#define WS_PB 8192
#define WS_ORDER 16384

// Fused single-block counting sort: zero + count + pad8-scan + init + scatter.
__global__ __launch_bounds__(1024) void sort_kernel(const int* __restrict__ r_idx,
                                                    int* __restrict__ order) {
  __shared__ int s_cnt[1024];
  __shared__ int s_cur[1024];
  __shared__ int s_wsum[16];
  const int tid = threadIdx.x, lane = tid & 63, wave = tid >> 6;
  s_cnt[tid] = 0;
  __syncthreads();
  int my[8];
#pragma unroll
  for (int k = 0; k < 8; ++k) {
    my[k] = r_idx[tid + k * 1024];
    atomicAdd(&s_cnt[my[k]], 1);
  }
  __syncthreads();
  const int c = (s_cnt[tid] + 7) & ~7;  // pad runs to multiple of 8
  int v = c;
#pragma unroll
  for (int o = 1; o < 64; o <<= 1) {
    int u = __shfl_up(v, o, 64);
    if (lane >= o) v += u;
  }
  if (lane == 63) s_wsum[wave] = v;
  __syncthreads();
  int woff = 0;
  for (int w = 0; w < wave; ++w) woff += s_wsum[w];
  s_cur[tid] = woff + v - c;
  for (int i = tid; i < ORDER_CAP; i += 1024) order[i] = -1;
  __syncthreads();
#pragma unroll
  for (int k = 0; k < 8; ++k) {
    int p = atomicAdd(&s_cur[my[k]], 1);
    order[p] = tid + k * 1024;
  }
}

__device__ inline float2 dvec(const float* __restrict__ b, int c0) {
  float2 h = *(const float2*)(b + c0);
  float2 r = *(const float2*)(b + DIM + c0);
  float2 t = *(const float2*)(b + 2 * DIM + c0);
  return make_float2(fabsf(h.x + r.x - t.x), fabsf(h.y + r.y - t.y));
}

// BARRIER-FREE E=8: 2 waves per 8-element same-relation group; wave half h
// covers rows [64h, 64h+64) for all 8 elements -> W read once per 8 elems
// (~95 MB vs R7's 179 MB). d staged wave-private (full 128 dims, 8 elems) in
// stride-40 units: unit l (dims 2l, 2l+1) at l*40 floats:
//   [0:4) dp.e0-3 dim2l | [4:8) dp.e4-7 | [8:16) dn | [16:32) same dim2l+1
// Hot-loop reads are 2-address broadcasts (free). Epilogue d via register
// __shfl (zero LDS reads). NO __syncthreads anywhere.
__global__ __launch_bounds__(256) void score_kernel(
    const float* __restrict__ pos_b, const float* __restrict__ neg_b,
    const int* __restrict__ r_idx, const float* __restrict__ rel_emb,
    const int* __restrict__ order, float* __restrict__ pA,
    float* __restrict__ pB) {
  __shared__ float s_d[4][64 * 40];  // 10240 B per wave, 40 KB per block
  const int tid = threadIdx.x, lane = tid & 63, wave = tid >> 6;
  const int phys = blockIdx.x;
  const int lb = (phys & 7) * (GRID / 8) + (phys >> 3);  // bijective, 952=8*119
  const int pair = wave >> 1, half = wave & 1;
  const int g = lb * 2 + pair;

  int4 ea = *(const int4*)(order + g * 8);
  if (ea.x < 0) return;  // wave-uniform empty group
  int4 eb = *(const int4*)(order + g * 8 + 4);

  const int c0 = lane * 2;
  const int r = r_idx[ea.x];
  const int e[8] = {ea.x, ea.y, ea.z, ea.w, eb.x, eb.y, eb.z, eb.w};
  const float2 z = make_float2(0.f, 0.f);
  float2 dp[8], dn[8];
#pragma unroll
  for (int i = 0; i < 8; ++i) {
    const bool vv = e[i] >= 0;
    const int idx = vv ? e[i] : ea.x;
    dp[i] = vv ? dvec(pos_b + (size_t)idx * 3 * DIM, c0) : z;
    dn[i] = vv ? dvec(neg_b + (size_t)idx * 3 * DIM, c0) : z;
  }

  // ---- wave-private stage (no barrier; in-wave lgkmcnt ordering) ----
  {
    float* u = &s_d[wave][lane * 40];
    *(float4*)(u + 0)  = make_float4(dp[0].x, dp[1].x, dp[2].x, dp[3].x);
    *(float4*)(u + 4)  = make_float4(dp[4].x, dp[5].x, dp[6].x, dp[7].x);
    *(float4*)(u + 8)  = make_float4(dn[0].x, dn[1].x, dn[2].x, dn[3].x);
    *(float4*)(u + 12) = make_float4(dn[4].x, dn[5].x, dn[6].x, dn[7].x);
    *(float4*)(u + 16) = make_float4(dp[0].y, dp[1].y, dp[2].y, dp[3].y);
    *(float4*)(u + 20) = make_float4(dp[4].y, dp[5].y, dp[6].y, dp[7].y);
    *(float4*)(u + 24) = make_float4(dn[0].y, dn[1].y, dn[2].y, dn[3].y);
    *(float4*)(u + 28) = make_float4(dn[4].y, dn[5].y, dn[6].y, dn[7].y);
  }

  const int lam = lane & 31, rsel = lane >> 5;
  const int colb = lam * 4;
  const float* W = rel_emb + (size_t)r * (DIM * DIM) +
                   (size_t)(half * 64 + rsel) * DIM + colb;
  // row = 64*half + 2*it + rsel -> unit = 32*half + it, parity ofs rsel*16
  const float* dbase = &s_d[wave][(half * 32) * 40 + rsel * 16];

  const float4 fz = make_float4(0.f, 0.f, 0.f, 0.f);
  float4 ap0 = fz, ap1 = fz, ap2 = fz, ap3 = fz;
  float4 ap4 = fz, ap5 = fz, ap6 = fz, ap7 = fz;
  float4 an0 = fz, an1 = fz, an2 = fz, an3 = fz;
  float4 an4 = fz, an5 = fz, an6 = fz, an7 = fz;

#define FMA4(ACC, D, WV)          \
  ACC.x = fmaf(D, WV.x, ACC.x);   \
  ACC.y = fmaf(D, WV.y, ACC.y);   \
  ACC.z = fmaf(D, WV.z, ACC.z);   \
  ACC.w = fmaf(D, WV.w, ACC.w);

#pragma unroll 8
  for (int it = 0; it < 32; ++it) {
    float4 wv = *(const float4*)(W + (size_t)(it * 2) * DIM);
    const float* dd = dbase + it * 40;
    float4 p0 = *(const float4*)(dd + 0);   // 2-addr broadcast
    float4 p1 = *(const float4*)(dd + 4);
    float4 n0 = *(const float4*)(dd + 8);
    float4 n1 = *(const float4*)(dd + 12);
    FMA4(ap0, p0.x, wv) FMA4(ap1, p0.y, wv)
    FMA4(ap2, p0.z, wv) FMA4(ap3, p0.w, wv)
    FMA4(ap4, p1.x, wv) FMA4(ap5, p1.y, wv)
    FMA4(ap6, p1.z, wv) FMA4(ap7, p1.w, wv)
    FMA4(an0, n0.x, wv) FMA4(an1, n0.y, wv)
    FMA4(an2, n0.z, wv) FMA4(an3, n0.w, wv)
    FMA4(an4, n1.x, wv) FMA4(an5, n1.y, wv)
    FMA4(an6, n1.z, wv) FMA4(an7, n1.w, wv)
  }
#undef FMA4

  // ---- epilogue: d for cols 4lam..4lam+3 lives in lanes 2lam, 2lam+1 ----
  const int sl0 = lam * 2, sl1 = sl0 + 1;
  float s[8];
#define EPI(I, AP, AN)                                                   \
  {                                                                      \
    float pa = __shfl(dp[I].x, sl0, 64), pb = __shfl(dp[I].y, sl0, 64);  \
    float pc = __shfl(dp[I].x, sl1, 64), pd = __shfl(dp[I].y, sl1, 64);  \
    float na = __shfl(dn[I].x, sl0, 64), nb = __shfl(dn[I].y, sl0, 64);  \
    float nc = __shfl(dn[I].x, sl1, 64), nd = __shfl(dn[I].y, sl1, 64);  \
    s[I] = AP.x * pa + AP.y * pb + AP.z * pc + AP.w * pd -               \
           (AN.x * na + AN.y * nb + AN.z * nc + AN.w * nd);              \
  }
  EPI(0, ap0, an0) EPI(1, ap1, an1) EPI(2, ap2, an2) EPI(3, ap3, an3)
  EPI(4, ap4, an4) EPI(5, ap5, an5) EPI(6, ap6, an6) EPI(7, ap7, an7)
#undef EPI

#pragma unroll
  for (int o = 32; o > 0; o >>= 1) {
#pragma unroll
    for (int i = 0; i < 8; ++i) s[i] += __shfl_xor(s[i], o, 64);
  }
  float* P = half ? pB : pA;
  if (lane == 0) {
#pragma unroll
    for (int i = 0; i < 8; ++i)
      if (e[i] >= 0) P[e[i]] = s[i];
  }
}

__global__ __launch_bounds__(256) void reduce_kernel(const float* __restrict__ pA,
                                                     const float* __restrict__ pB,
                                                     float* __restrict__ out) {
  float acc = 0.f;
  for (int i = threadIdx.x; i < BATCH; i += 256) {
    float v = MARGIN + pA[i] + pB[i];
    acc += (v > 0.f) ? v : 0.f;
  }
#pragma unroll
  for (int o = 32; o > 0; o >>= 1) acc += __shfl_xor(acc, o, 64);
  __shared__ float s[4];
  const int lane = threadIdx.x & 63, wave = threadIdx.x >> 6;
  if (lane == 0) s[wave] = acc;
  __syncthreads();
  if (threadIdx.x == 0) out[0] = (s[0] + s[1] + s[2] + s[3]) * (1.0f / BATCH);
}

extern "C" void kernel_launch(void* const* d_in, const int* in_sizes, int n_in,
                              void* d_out, int out_size, void* d_ws, size_t ws_size,
                              hipStream_t stream) {
  const float* pos_b = (const float*)d_in[0];
  const float* neg_b = (const float*)d_in[1];
  const int* r_idx = (const int*)d_in[2];
  const float* rel_emb = (const float*)d_in[3];
  float* out = (float*)d_out;

  float* pA = (float*)d_ws + WS_PA;
  float* pB = (float*)d_ws + WS_PB;
  int* order = (int*)d_ws + WS_ORDER;

  sort_kernel<<<1, 1024, 0, stream>>>(r_idx, order);
  score_kernel<<<GRID, 256, 0, stream>>>(pos_b, neg_b, r_idx, rel_emb, order,
                                         pA, pB);
  reduce_kernel<<<1, 256, 0, stream>>>(pA, pB, out);
}

// Round 15
// 46.167 us; speedup vs baseline: 7.1305x; 1.0512x over previous
//
#include <hip/hip_runtime.h>

#define BATCH 8192
#define DIM 128
#define NREL 1000
#define MARGIN 1.0f
#define GRID 2816       // = 8*352 blocks, one per padded 4-elem group
#define ORDER_CAP 11264 // >= max padded total (8192 + 3*1000 = 11192) = GRID*4

// ws layout (4 B units): partial4[32768] | order[11264]
#define WS_PARTIAL 0
#define WS_ORDER 32768

// Fused single-block counting sort (R7-proven): zero+count+pad4-scan+scatter.
__global__ __launch_bounds__(1024) void sort_kernel(const int* __restrict__ r_idx,
                                                    int* __restrict__ order) {
  __shared__ int s_cnt[1024];
  __shared__ int s_cur[1024];
  __shared__ int s_wsum[16];
  const int tid = threadIdx.x, lane = tid & 63, wave = tid >> 6;
  s_cnt[tid] = 0;
  __syncthreads();
  int my[8];
#pragma unroll
  for (int k = 0; k < 8; ++k) {
    my[k] = r_idx[tid + k * 1024];
    atomicAdd(&s_cnt[my[k]], 1);
  }
  __syncthreads();
  const int c = (s_cnt[tid] + 3) & ~3;  // pad runs to multiple of 4
  int v = c;
#pragma unroll
  for (int o = 1; o < 64; o <<= 1) {
    int u = __shfl_up(v, o, 64);
    if (lane >= o) v += u;
  }
  if (lane == 63) s_wsum[wave] = v;
  __syncthreads();
  int woff = 0;
  for (int w = 0; w < wave; ++w) woff += s_wsum[w];
  s_cur[tid] = woff + v - c;
  for (int i = tid; i < ORDER_CAP; i += 1024) order[i] = -1;
  __syncthreads();
#pragma unroll
  for (int k = 0; k < 8; ++k) {
    int p = atomicAdd(&s_cur[my[k]], 1);
    order[p] = tid + k * 1024;
  }
}

__device__ inline float2 dvec(const float* __restrict__ b, int c0) {
  float2 h = *(const float2*)(b + c0);
  float2 r = *(const float2*)(b + DIM + c0);
  float2 t = *(const float2*)(b + 2 * DIM + c0);
  return make_float2(fabsf(h.x + r.x - t.x), fabsf(h.y + r.y - t.y));
}

// SHORT-CHAIN, BARRIER-FREE: one block per 4-element group; wave q covers
// W rows [32q, 32q+32) independently (16-iter chain, half of R7's).
// Each wave stages its OWN d copy (R7 stride-20 conflict-free layout);
// the 4x-redundant d global loads are L1-deduped (issued together at block
// start). Epilogue via register __shfl. Quarter-partials -> partial4[e][q].
// NO __syncthreads anywhere.
__global__ __launch_bounds__(256) void score_kernel(
    const float* __restrict__ pos_b, const float* __restrict__ neg_b,
    const int* __restrict__ r_idx, const float* __restrict__ rel_emb,
    const int* __restrict__ order, float* __restrict__ partial4) {
  __shared__ float s_d[4][64 * 20];  // 5120 B per wave, 20 KB per block
  const int tid = threadIdx.x, lane = tid & 63, wave = tid >> 6;
  const int phys = blockIdx.x;
  const int g = (phys & 7) * (GRID / 8) + (phys >> 3);  // bijective, 2816=8*352
  int4 es = *(const int4*)(order + g * 4);
  if (es.x < 0) return;  // block-uniform empty group (no barriers exist)

  const int c0 = lane * 2;
  const int r = r_idx[es.x];
  const bool v1 = es.y >= 0, v2 = es.z >= 0, v3 = es.w >= 0;
  const int e1 = v1 ? es.y : es.x, e2 = v2 ? es.z : es.x, e3 = v3 ? es.w : es.x;

  const float2 z = make_float2(0.f, 0.f);
  float2 dp0 = dvec(pos_b + (size_t)es.x * 3 * DIM, c0);
  float2 dn0 = dvec(neg_b + (size_t)es.x * 3 * DIM, c0);
  float2 dp1 = v1 ? dvec(pos_b + (size_t)e1 * 3 * DIM, c0) : z;
  float2 dn1 = v1 ? dvec(neg_b + (size_t)e1 * 3 * DIM, c0) : z;
  float2 dp2 = v2 ? dvec(pos_b + (size_t)e2 * 3 * DIM, c0) : z;
  float2 dn2 = v2 ? dvec(neg_b + (size_t)e2 * 3 * DIM, c0) : z;
  float2 dp3 = v3 ? dvec(pos_b + (size_t)e3 * 3 * DIM, c0) : z;
  float2 dn3 = v3 ? dvec(neg_b + (size_t)e3 * 3 * DIM, c0) : z;

  // wave-private stage (in-wave lgkmcnt ordering; no barrier). Lane-major
  // stride-20: writes sweep all 8 bank-quads -> conflict-free.
  {
    float* myd = &s_d[wave][lane * 20];
    *(float4*)(myd + 0)  = make_float4(dp0.x, dp1.x, dp2.x, dp3.x);
    *(float4*)(myd + 4)  = make_float4(dn0.x, dn1.x, dn2.x, dn3.x);
    *(float4*)(myd + 8)  = make_float4(dp0.y, dp1.y, dp2.y, dp3.y);
    *(float4*)(myd + 12) = make_float4(dn0.y, dn1.y, dn2.y, dn3.y);
  }

  const int lam = lane & 31, rsel = lane >> 5;
  const int colb = lam * 4;
  // wave q covers rows [32q, 32q+32): row = 32q + 2*it + rsel, it < 16
  const float* W = rel_emb + (size_t)r * (DIM * DIM) +
                   (size_t)(wave * 32 + rsel) * DIM + colb;
  // unit u = row>>1 = 16q + it; parity rsel -> +8
  const float* dbase = &s_d[wave][(wave * 16) * 20 + rsel * 8];

  const float4 fz = make_float4(0.f, 0.f, 0.f, 0.f);
  float4 ap0 = fz, ap1 = fz, ap2 = fz, ap3 = fz;
  float4 an0 = fz, an1 = fz, an2 = fz, an3 = fz;

#define FMA4(ACC, D, WV)          \
  ACC.x = fmaf(D, WV.x, ACC.x);   \
  ACC.y = fmaf(D, WV.y, ACC.y);   \
  ACC.z = fmaf(D, WV.z, ACC.z);   \
  ACC.w = fmaf(D, WV.w, ACC.w);

#pragma unroll 16
  for (int it = 0; it < 16; ++it) {
    float4 wv = *(const float4*)(W + (size_t)(it * 2) * DIM);
    float4 ddp = *(const float4*)(dbase + it * 20);      // 2-addr broadcast
    float4 ddn = *(const float4*)(dbase + it * 20 + 4);  // 2-addr broadcast
    FMA4(ap0, ddp.x, wv) FMA4(ap1, ddp.y, wv)
    FMA4(ap2, ddp.z, wv) FMA4(ap3, ddp.w, wv)
    FMA4(an0, ddn.x, wv) FMA4(an1, ddn.y, wv)
    FMA4(an2, ddn.z, wv) FMA4(an3, ddn.w, wv)
  }
#undef FMA4

  // epilogue: d for cols 4lam..4lam+3 lives in lanes 2lam, 2lam+1 regs.
  const int sl0 = lam * 2, sl1 = sl0 + 1;
#define GET4(OUT0, OUT1, OUT2, OUT3, V)   \
  OUT0 = __shfl(V.x, sl0, 64);            \
  OUT1 = __shfl(V.y, sl0, 64);            \
  OUT2 = __shfl(V.x, sl1, 64);            \
  OUT3 = __shfl(V.y, sl1, 64);
  float a, b, c, d, e, f, gg, h;
  float s0, s1, s2, s3;
  GET4(a, b, c, d, dp0) GET4(e, f, gg, h, dn0)
  s0 = ap0.x * a + ap0.y * b + ap0.z * c + ap0.w * d -
       (an0.x * e + an0.y * f + an0.z * gg + an0.w * h);
  GET4(a, b, c, d, dp1) GET4(e, f, gg, h, dn1)
  s1 = ap1.x * a + ap1.y * b + ap1.z * c + ap1.w * d -
       (an1.x * e + an1.y * f + an1.z * gg + an1.w * h);
  GET4(a, b, c, d, dp2) GET4(e, f, gg, h, dn2)
  s2 = ap2.x * a + ap2.y * b + ap2.z * c + ap2.w * d -
       (an2.x * e + an2.y * f + an2.z * gg + an2.w * h);
  GET4(a, b, c, d, dp3) GET4(e, f, gg, h, dn3)
  s3 = ap3.x * a + ap3.y * b + ap3.z * c + ap3.w * d -
       (an3.x * e + an3.y * f + an3.z * gg + an3.w * h);
#undef GET4

#pragma unroll
  for (int o = 32; o > 0; o >>= 1) {
    s0 += __shfl_xor(s0, o, 64);
    s1 += __shfl_xor(s1, o, 64);
    s2 += __shfl_xor(s2, o, 64);
    s3 += __shfl_xor(s3, o, 64);
  }
  if (lane == 0) {
    partial4[es.x * 4 + wave] = s0;
    if (v1) partial4[es.y * 4 + wave] = s1;
    if (v2) partial4[es.z * 4 + wave] = s2;
    if (v3) partial4[es.w * 4 + wave] = s3;
  }
}

__global__ __launch_bounds__(256) void reduce_kernel(const float* __restrict__ partial4,
                                                     float* __restrict__ out) {
  float acc = 0.f;
  for (int i = threadIdx.x; i < BATCH; i += 256) {
    float4 q = *(const float4*)(partial4 + i * 4);
    float v = MARGIN + q.x + q.y + q.z + q.w;
    acc += (v > 0.f) ? v : 0.f;
  }
#pragma unroll
  for (int o = 32; o > 0; o >>= 1) acc += __shfl_xor(acc, o, 64);
  __shared__ float s[4];
  const int lane = threadIdx.x & 63, wave = threadIdx.x >> 6;
  if (lane == 0) s[wave] = acc;
  __syncthreads();
  if (threadIdx.x == 0) out[0] = (s[0] + s[1] + s[2] + s[3]) * (1.0f / BATCH);
}

extern "C" void kernel_launch(void* const* d_in, const int* in_sizes, int n_in,
                              void* d_out, int out_size, void* d_ws, size_t ws_size,
                              hipStream_t stream) {
  const float* pos_b = (const float*)d_in[0];
  const float* neg_b = (const float*)d_in[1];
  const int* r_idx = (const int*)d_in[2];
  const float* rel_emb = (const float*)d_in[3];
  float* out = (float*)d_out;

  float* partial4 = (float*)d_ws + WS_PARTIAL;
  int* order = (int*)d_ws + WS_ORDER;

  sort_kernel<<<1, 1024, 0, stream>>>(r_idx, order);
  score_kernel<<<GRID, 256, 0, stream>>>(pos_b, neg_b, r_idx, rel_emb, order,
                                         partial4);
  reduce_kernel<<<1, 256, 0, stream>>>(partial4, out);
}